// Round 11
// baseline (153.628 us; speedup 1.0000x reference)
//
#include <hip/hip_runtime.h>

#define B_    4
#define C_    256
#define Kk    7
#define GC_   16
#define G_    16
#define RED_  64
#define H_    56
#define W_    56
#define HW_   3136
#define KK_   49
#define KG_   784
#define NP_   12544

typedef float  f4    __attribute__((ext_vector_type(4)));
typedef float  f32x4 __attribute__((ext_vector_type(4)));
typedef __bf16 bf16x8 __attribute__((ext_vector_type(8)));
typedef __bf16 bf16x4 __attribute__((ext_vector_type(4)));
typedef unsigned short u16;
typedef u16    u16x4 __attribute__((ext_vector_type(4)));
typedef u16    u16x8 __attribute__((ext_vector_type(8)));

__device__ __forceinline__ f4 ld4(const float* p) { return *(const f4*)p; }
__device__ __forceinline__ void st4(float* p, f4 v) { *(f4*)p = v; }
__device__ __forceinline__ float bf2f(u16 u) {
    return __uint_as_float(((unsigned)u) << 16);
}

// ---------------------------------------------------------------------------
// xt: transpose x f32 [b][c][p] -> xt bf16 [P][256] (c contiguous).  (verified)
__global__ __launch_bounds__(256) void xt_kernel(const float* __restrict__ x,
                                                 __bf16* __restrict__ xt) {
    __shared__ __bf16 lt[64][68];
    const int tid = threadIdx.x;
    const int P0  = blockIdx.x * 64;
    const int c0  = blockIdx.y * 64;
    const int b   = P0 / HW_;
    const int p0  = P0 - b * HW_;

    const int pq  = tid & 15;
    const int crb = tid >> 4;
#pragma unroll
    for (int i = 0; i < 4; ++i) {
        const int cr = crb + i * 16;
        const f4 v = ld4(x + (size_t)(b * C_ + c0 + cr) * HW_ + p0 + pq * 4);
#pragma unroll
        for (int j = 0; j < 4; ++j) lt[pq * 4 + j][cr] = (__bf16)v[j];
    }
    __syncthreads();
    const int cq  = tid & 15;
    const int plb = tid >> 4;
#pragma unroll
    for (int i = 0; i < 4; ++i) {
        const int pl = plb + i * 16;
        const bf16x4 rv = *(const bf16x4*)&lt[pl][cq * 4];
        *(bf16x4*)(xt + (size_t)(P0 + pl) * C_ + c0 + cq * 4) = rv;
    }
}

// ---------------------------------------------------------------------------
// gen1m2 (MFMA): t[P][64] bf16 = relu(w1 @ x + b1).  (verified r8)
__global__ __launch_bounds__(256) void gen1m2(const __bf16* __restrict__ xt,
                                              const float* __restrict__ w1,
                                              const float* __restrict__ b1,
                                              __bf16* __restrict__ t) {
    __shared__ __bf16 w1s[64][260];        // 64 rows x 256 c (+4 pad)
    const int tid  = threadIdx.x;
    const int lane = tid & 63;
    const int wave = tid >> 6;
    const int row  = lane & 15;
    const int kg   = lane >> 4;
    const int P0w  = blockIdx.x * 64 + wave * 16;

    const __bf16* bp = xt + (size_t)(P0w + row) * C_ + kg * 8;
    bf16x8 bv[8];
#pragma unroll
    for (int ks = 0; ks < 8; ++ks) bv[ks] = *(const bf16x8*)(bp + ks * 32);

#pragma unroll
    for (int i = 0; i < 16; ++i) {
        const int q  = tid + i * 256;
        const int r  = q >> 6;
        const int c0 = (q & 63) * 4;
        const f4 v = ld4(w1 + (size_t)r * C_ + c0);
        bf16x4 pk;
#pragma unroll
        for (int j = 0; j < 4; ++j) pk[j] = (__bf16)v[j];
        *(bf16x4*)&w1s[r][c0] = pk;
    }
    __syncthreads();

    f32x4 acc[4] = {f32x4(0.f), f32x4(0.f), f32x4(0.f), f32x4(0.f)};
#pragma unroll
    for (int ks = 0; ks < 8; ++ks)
#pragma unroll
        for (int mt = 0; mt < 4; ++mt) {
            const bf16x8 af = *(const bf16x8*)&w1s[mt * 16 + row][ks * 32 + kg * 8];
            acc[mt] = __builtin_amdgcn_mfma_f32_16x16x32_bf16(af, bv[ks], acc[mt], 0, 0, 0);
        }

#pragma unroll
    for (int mt = 0; mt < 4; ++mt) {
        const f4 bias = ld4(b1 + mt * 16 + kg * 4);
        bf16x4 pk;
#pragma unroll
        for (int j = 0; j < 4; ++j)
            pk[j] = (__bf16)fmaxf(acc[mt][j] + bias[j], 0.f);
        *(bf16x4*)(t + (size_t)(P0w + row) * RED_ + mt * 16 + kg * 4) = pk;
    }
}

// ---------------------------------------------------------------------------
// gen2_mfma3: wgt = w2 @ t + b2, coalesced stores via per-wave LDS transpose.
// FIX vs r9: batch index derived per-WAVE (64 | 3136), not per-block
// (3136/256 = 12.25 -> a 256-px block can cross the batch boundary).
__global__ __launch_bounds__(256) void gen2_mfma3(const __bf16* __restrict__ t,
                                                  const float* __restrict__ w2,
                                                  const float* __restrict__ b2,
                                                  __bf16* __restrict__ wgt) {
    __shared__ __bf16 w2s[64][68];         // 8704 B
    __shared__ u16    sw[4][16][72];       // per-wave 16k x 64px slice, 9216 B
    const int tid  = threadIdx.x;
    const int lane = tid & 63;
    const int wave = tid >> 6;
    const int row  = lane & 15;
    const int kg   = lane >> 4;
    const int Pw   = blockIdx.x * 256 + wave * 64;   // wave's first global pixel
    const int b    = Pw / HW_;             // 64 | 3136: wave within one batch
    const int pw   = Pw - b * HW_;
    const int k0   = blockIdx.y * 64;
    const int nMt  = (blockIdx.y == 12) ? 1 : 4;     // 784 = 12*64 + 16

    bf16x8 bfrag[4][2];
#pragma unroll
    for (int cg = 0; cg < 4; ++cg)
#pragma unroll
        for (int ks = 0; ks < 2; ++ks)
            bfrag[cg][ks] = *(const bf16x8*)(t + (size_t)(Pw + cg * 16 + row) * RED_
                                               + ks * 32 + kg * 8);

#pragma unroll
    for (int i = 0; i < 4; ++i) {
        const int q  = tid + i * 256;
        const int r  = q >> 4;
        const int c0 = (q & 15) * 4;
        f4 v = {0.f, 0.f, 0.f, 0.f};
        if (k0 + r < KG_) v = ld4(w2 + (size_t)(k0 + r) * RED_ + c0);
        bf16x4 pk;
#pragma unroll
        for (int j = 0; j < 4; ++j) pk[j] = (__bf16)v[j];
        *(bf16x4*)&w2s[r][c0] = pk;
    }
    __syncthreads();

    for (int mt = 0; mt < nMt; ++mt) {
        const bf16x8 afr0 = *(const bf16x8*)&w2s[mt * 16 + row][kg * 8];
        const bf16x8 afr1 = *(const bf16x8*)&w2s[mt * 16 + row][32 + kg * 8];
        f32x4 acc[4] = {f32x4(0.f), f32x4(0.f), f32x4(0.f), f32x4(0.f)};
#pragma unroll
        for (int cg = 0; cg < 4; ++cg) {
            acc[cg] = __builtin_amdgcn_mfma_f32_16x16x32_bf16(afr0, bfrag[cg][0], acc[cg], 0, 0, 0);
            acc[cg] = __builtin_amdgcn_mfma_f32_16x16x32_bf16(afr1, bfrag[cg][1], acc[cg], 0, 0, 0);
        }
        const f4 bias = ld4(b2 + k0 + mt * 16 + kg * 4);
        // transpose through per-wave LDS slice (within-wave exchange, in-order)
#pragma unroll
        for (int cg = 0; cg < 4; ++cg)
#pragma unroll
            for (int j = 0; j < 4; ++j) {
                const __bf16 v = (__bf16)(acc[cg][j] + bias[j]);
                sw[wave][kg * 4 + j][cg * 16 + row] = *(const u16*)&v;
            }
        // cooperative coalesced store: 16 rows x 64 px = 128 x u16x8 chunks
#pragma unroll
        for (int u = 0; u < 2; ++u) {
            const int r16 = (lane >> 3) + u * 8;
            const int ch  = lane & 7;
            const u16x8 v = *(const u16x8*)&sw[wave][r16][ch * 8];
            *(u16x8*)((u16*)wgt + ((size_t)b * KG_ + k0 + mt * 16 + r16) * HW_
                                + pw + ch * 8) = v;
        }
    }
}

// ---------------------------------------------------------------------------
// inv v2: bf16 x staged in LDS (converted in flight). LDS 45KB -> 3 blocks/CU.
// xs pad col = px+3. grid (14, 16, 4), block 256.
#define BR_   4
#define XR_   10
#define XPW_  72
__global__ __launch_bounds__(256) void inv_kernel(const float* __restrict__ x,
                                                  const u16* __restrict__ wgt,
                                                  float* __restrict__ out) {
    __shared__ u16 xs[GC_][XR_][XPW_];     // 23040 B
    __shared__ u16 wsm[KK_][BR_][W_];      // 21952 B  (total 44992 B)
    const int tid = threadIdx.x;
    const int r0  = blockIdx.x * BR_;
    const int g   = blockIdx.y;
    const int b   = blockIdx.z;

    // stage xs: 16 ch x 10 rows x 18 col-quads = 2880 units (f32 -> bf16)
    for (int idx = tid; idx < GC_ * XR_ * 18; idx += 256) {
        const int c   = idx / (XR_ * 18);
        const int rem = idx - c * (XR_ * 18);
        const int hr  = rem / 18;
        const int qd  = rem - hr * 18;
        const int h   = r0 - 3 + hr;
        const int px0 = qd * 4 - 3;
        f4 v = {0.f, 0.f, 0.f, 0.f};
        if (h >= 0 && h < H_) {
            const float* xr_ = x + (size_t)(b * C_ + g * GC_ + c) * HW_ + h * W_;
            if (qd >= 1 && qd <= 13) {
                v = ld4(xr_ + px0);
            } else {
#pragma unroll
                for (int j = 0; j < 4; ++j) {
                    const int px = px0 + j;
                    if (px >= 0 && px < W_) v[j] = xr_[px];
                }
            }
        }
        u16x4 pk;
#pragma unroll
        for (int j = 0; j < 4; ++j) {
            const __bf16 bv = (__bf16)v[j];
            pk[j] = *(const u16*)&bv;
        }
        *(u16x4*)&xs[c][hr][qd * 4] = pk;
    }
    // stage taps: 49 k x 4 rows x 7 b128-chunks = 1372 units
    for (int idx = tid; idx < KK_ * BR_ * 7; idx += 256) {
        const int k   = idx / (BR_ * 7);
        const int rem = idx - k * (BR_ * 7);
        const int r   = rem / 7;
        const int ch  = rem - r * 7;
        const u16x8 v = *(const u16x8*)(wgt + ((size_t)b * KG_ + (size_t)g * KK_ + k) * HW_
                                            + (r0 + r) * W_ + ch * 8);
        *(u16x8*)&wsm[k][r][ch * 8] = v;
    }
    __syncthreads();

    if (tid >= 224) return;
    const int cq  = tid % 14;
    const int r   = (tid / 14) & 3;
    const int cg4 = tid / 56;

    f4 acc[4] = {f4(0.f), f4(0.f), f4(0.f), f4(0.f)};
#pragma unroll
    for (int kh = 0; kh < Kk; ++kh) {
        float tf[7][4];
#pragma unroll
        for (int kw = 0; kw < 7; ++kw) {
            const u16x4 tv = *(const u16x4*)&wsm[kh * 7 + kw][r][cq * 4];
#pragma unroll
            for (int j = 0; j < 4; ++j) tf[kw][j] = bf2f(tv[j]);
        }
        const int hr = r + kh;
#pragma unroll
        for (int ci = 0; ci < 4; ++ci) {
            const u16* xrow = &xs[cg4 * 4 + ci][hr][cq * 4];
            float xw[12];
#pragma unroll
            for (int q = 0; q < 3; ++q) {
                const u16x4 xv = *(const u16x4*)(xrow + q * 4);
#pragma unroll
                for (int j = 0; j < 4; ++j) xw[q * 4 + j] = bf2f(xv[j]);
            }
#pragma unroll
            for (int kw = 0; kw < 7; ++kw)
#pragma unroll
                for (int j = 0; j < 4; ++j)
                    acc[ci][j] = fmaf(tf[kw][j], xw[j + kw], acc[ci][j]);
        }
    }

#pragma unroll
    for (int ci = 0; ci < 4; ++ci)
        st4(out + (size_t)(b * C_ + g * GC_ + cg4 * 4 + ci) * HW_ + (r0 + r) * W_ + cq * 4,
            acc[ci]);
}

// ---------------------------------------------------------------------------
extern "C" void kernel_launch(void* const* d_in, const int* in_sizes, int n_in,
                              void* d_out, int out_size, void* d_ws, size_t ws_size,
                              hipStream_t stream) {
    const float* x  = (const float*)d_in[0];
    const float* w1 = (const float*)d_in[1];
    const float* b1 = (const float*)d_in[2];
    const float* w2 = (const float*)d_in[3];
    const float* b2 = (const float*)d_in[4];
    float* out = (float*)d_out;

    // ws: xt bf16 (6.42 MB) | t bf16 (1.6 MB) | wgt bf16 (19.7 MB)
    char* ws = (char*)d_ws;
    __bf16* xt  = (__bf16*)ws;
    __bf16* t   = (__bf16*)(ws + (size_t)NP_ * C_ * 2);
    __bf16* wgt = (__bf16*)(ws + (size_t)NP_ * C_ * 2 + (size_t)NP_ * RED_ * 2);

    xt_kernel  <<<dim3(NP_ / 64, C_ / 64), 256, 0, stream>>>(x, xt);
    gen1m2     <<<dim3(NP_ / 64),          256, 0, stream>>>(xt, w1, b1, t);
    gen2_mfma3 <<<dim3(NP_ / 256, 13),     256, 0, stream>>>(t, w2, b2, wgt);
    inv_kernel <<<dim3(14, G_, B_),        256, 0, stream>>>(x, (const u16*)wgt, out);
}

// Round 12
// 115.639 us; speedup vs baseline: 1.3285x; 1.3285x over previous
//
#include <hip/hip_runtime.h>

#define B_    4
#define C_    256
#define Kk    7
#define GC_   16
#define G_    16
#define RED_  64
#define H_    56
#define W_    56
#define HW_   3136
#define KK_   49
#define KG_   784
#define NP_   12544

typedef float  f4    __attribute__((ext_vector_type(4)));
typedef float  f32x4 __attribute__((ext_vector_type(4)));
typedef __bf16 bf16x8 __attribute__((ext_vector_type(8)));
typedef __bf16 bf16x4 __attribute__((ext_vector_type(4)));
typedef unsigned short u16;
typedef u16    u16x4 __attribute__((ext_vector_type(4)));
typedef u16    u16x8 __attribute__((ext_vector_type(8)));

__device__ __forceinline__ f4 ld4(const float* p) { return *(const f4*)p; }
__device__ __forceinline__ void st4(float* p, f4 v) { *(f4*)p = v; }
__device__ __forceinline__ float bf2f(u16 u) {
    return __uint_as_float(((unsigned)u) << 16);
}

// ---------------------------------------------------------------------------
// xt: transpose x f32 [b][c][p] -> xt bf16 [P][256] (c contiguous).  (verified)
__global__ __launch_bounds__(256) void xt_kernel(const float* __restrict__ x,
                                                 __bf16* __restrict__ xt) {
    __shared__ __bf16 lt[64][68];
    const int tid = threadIdx.x;
    const int P0  = blockIdx.x * 64;
    const int c0  = blockIdx.y * 64;
    const int b   = P0 / HW_;
    const int p0  = P0 - b * HW_;

    const int pq  = tid & 15;
    const int crb = tid >> 4;
#pragma unroll
    for (int i = 0; i < 4; ++i) {
        const int cr = crb + i * 16;
        const f4 v = ld4(x + (size_t)(b * C_ + c0 + cr) * HW_ + p0 + pq * 4);
#pragma unroll
        for (int j = 0; j < 4; ++j) lt[pq * 4 + j][cr] = (__bf16)v[j];
    }
    __syncthreads();
    const int cq  = tid & 15;
    const int plb = tid >> 4;
#pragma unroll
    for (int i = 0; i < 4; ++i) {
        const int pl = plb + i * 16;
        const bf16x4 rv = *(const bf16x4*)&lt[pl][cq * 4];
        *(bf16x4*)(xt + (size_t)(P0 + pl) * C_ + c0 + cq * 4) = rv;
    }
}

// ---------------------------------------------------------------------------
// gen1m2 (MFMA): t[P][64] bf16 = relu(w1 @ x + b1).  (verified r8)
__global__ __launch_bounds__(256) void gen1m2(const __bf16* __restrict__ xt,
                                              const float* __restrict__ w1,
                                              const float* __restrict__ b1,
                                              __bf16* __restrict__ t) {
    __shared__ __bf16 w1s[64][260];        // 64 rows x 256 c (+4 pad)
    const int tid  = threadIdx.x;
    const int lane = tid & 63;
    const int wave = tid >> 6;
    const int row  = lane & 15;
    const int kg   = lane >> 4;
    const int P0w  = blockIdx.x * 64 + wave * 16;

    const __bf16* bp = xt + (size_t)(P0w + row) * C_ + kg * 8;
    bf16x8 bv[8];
#pragma unroll
    for (int ks = 0; ks < 8; ++ks) bv[ks] = *(const bf16x8*)(bp + ks * 32);

#pragma unroll
    for (int i = 0; i < 16; ++i) {
        const int q  = tid + i * 256;
        const int r  = q >> 6;
        const int c0 = (q & 63) * 4;
        const f4 v = ld4(w1 + (size_t)r * C_ + c0);
        bf16x4 pk;
#pragma unroll
        for (int j = 0; j < 4; ++j) pk[j] = (__bf16)v[j];
        *(bf16x4*)&w1s[r][c0] = pk;
    }
    __syncthreads();

    f32x4 acc[4] = {f32x4(0.f), f32x4(0.f), f32x4(0.f), f32x4(0.f)};
#pragma unroll
    for (int ks = 0; ks < 8; ++ks)
#pragma unroll
        for (int mt = 0; mt < 4; ++mt) {
            const bf16x8 af = *(const bf16x8*)&w1s[mt * 16 + row][ks * 32 + kg * 8];
            acc[mt] = __builtin_amdgcn_mfma_f32_16x16x32_bf16(af, bv[ks], acc[mt], 0, 0, 0);
        }

#pragma unroll
    for (int mt = 0; mt < 4; ++mt) {
        const f4 bias = ld4(b1 + mt * 16 + kg * 4);
        bf16x4 pk;
#pragma unroll
        for (int j = 0; j < 4; ++j)
            pk[j] = (__bf16)fmaxf(acc[mt][j] + bias[j], 0.f);
        *(bf16x4*)(t + (size_t)(P0w + row) * RED_ + mt * 16 + kg * 4) = pk;
    }
}

// ---------------------------------------------------------------------------
// gen2_mfma3: wgt = w2 @ t + b2, coalesced stores via per-wave LDS transpose.
// (r11: per-WAVE batch index — 64 | 3136; verified passing)
__global__ __launch_bounds__(256) void gen2_mfma3(const __bf16* __restrict__ t,
                                                  const float* __restrict__ w2,
                                                  const float* __restrict__ b2,
                                                  __bf16* __restrict__ wgt) {
    __shared__ __bf16 w2s[64][68];         // 8704 B
    __shared__ u16    sw[4][16][72];       // per-wave 16k x 64px slice, 9216 B
    const int tid  = threadIdx.x;
    const int lane = tid & 63;
    const int wave = tid >> 6;
    const int row  = lane & 15;
    const int kg   = lane >> 4;
    const int Pw   = blockIdx.x * 256 + wave * 64;   // wave's first global pixel
    const int b    = Pw / HW_;             // 64 | 3136: wave within one batch
    const int pw   = Pw - b * HW_;
    const int k0   = blockIdx.y * 64;
    const int nMt  = (blockIdx.y == 12) ? 1 : 4;     // 784 = 12*64 + 16

    bf16x8 bfrag[4][2];
#pragma unroll
    for (int cg = 0; cg < 4; ++cg)
#pragma unroll
        for (int ks = 0; ks < 2; ++ks)
            bfrag[cg][ks] = *(const bf16x8*)(t + (size_t)(Pw + cg * 16 + row) * RED_
                                               + ks * 32 + kg * 8);

#pragma unroll
    for (int i = 0; i < 4; ++i) {
        const int q  = tid + i * 256;
        const int r  = q >> 4;
        const int c0 = (q & 15) * 4;
        f4 v = {0.f, 0.f, 0.f, 0.f};
        if (k0 + r < KG_) v = ld4(w2 + (size_t)(k0 + r) * RED_ + c0);
        bf16x4 pk;
#pragma unroll
        for (int j = 0; j < 4; ++j) pk[j] = (__bf16)v[j];
        *(bf16x4*)&w2s[r][c0] = pk;
    }
    __syncthreads();

    for (int mt = 0; mt < nMt; ++mt) {
        const bf16x8 afr0 = *(const bf16x8*)&w2s[mt * 16 + row][kg * 8];
        const bf16x8 afr1 = *(const bf16x8*)&w2s[mt * 16 + row][32 + kg * 8];
        f32x4 acc[4] = {f32x4(0.f), f32x4(0.f), f32x4(0.f), f32x4(0.f)};
#pragma unroll
        for (int cg = 0; cg < 4; ++cg) {
            acc[cg] = __builtin_amdgcn_mfma_f32_16x16x32_bf16(afr0, bfrag[cg][0], acc[cg], 0, 0, 0);
            acc[cg] = __builtin_amdgcn_mfma_f32_16x16x32_bf16(afr1, bfrag[cg][1], acc[cg], 0, 0, 0);
        }
        const f4 bias = ld4(b2 + k0 + mt * 16 + kg * 4);
        // transpose through per-wave LDS slice (within-wave exchange, in-order)
#pragma unroll
        for (int cg = 0; cg < 4; ++cg)
#pragma unroll
            for (int j = 0; j < 4; ++j) {
                const __bf16 v = (__bf16)(acc[cg][j] + bias[j]);
                sw[wave][kg * 4 + j][cg * 16 + row] = *(const u16*)&v;
            }
        // cooperative coalesced store: 16 rows x 64 px = 128 x u16x8 chunks
#pragma unroll
        for (int u = 0; u < 2; ++u) {
            const int r16 = (lane >> 3) + u * 8;
            const int ch  = lane & 7;
            const u16x8 v = *(const u16x8*)&sw[wave][r16][ch * 8];
            *(u16x8*)((u16*)wgt + ((size_t)b * KG_ + k0 + mt * 16 + r16) * HW_
                                + pw + ch * 8) = v;
        }
    }
}

// ---------------------------------------------------------------------------
// inv v3: f32 xs in LDS (the r5/r8 proven conflict-free layout); taps read
// DIRECTLY from global (L1/L2-resident, 448B bursts). LDS 43.5KB -> 3 blk/CU.
// grid (14, 16, 4), block 256.
#define BR_  4
#define XR_  10
#define XST_ 68
__global__ __launch_bounds__(256) void inv_kernel(const float* __restrict__ x,
                                                  const u16* __restrict__ wgt,
                                                  float* __restrict__ out) {
    __shared__ float xs[GC_][XR_][XST_];   // 43520 B
    const int tid = threadIdx.x;
    const int r0  = blockIdx.x * BR_;
    const int g   = blockIdx.y;
    const int b   = blockIdx.z;

    // stage xs: 16 ch x 10 rows x 16 col-quads = 2560 quads (f32, 16B stores)
    for (int idx = tid; idx < GC_ * XR_ * 16; idx += 256) {
        const int c   = idx / (XR_ * 16);
        const int rem = idx - c * (XR_ * 16);
        const int hr  = rem >> 4;
        const int wq  = rem & 15;
        const int h   = r0 - 3 + hr;
        f4 v = {0.f, 0.f, 0.f, 0.f};
        if (h >= 0 && h < H_) {
            const float* xr_ = x + (size_t)(b * C_ + g * GC_ + c) * HW_ + h * W_;
            const int w0 = wq * 4 - 3;
            if (wq >= 1 && wq <= 13) {
                v = ld4(xr_ + w0);
            } else {
#pragma unroll
                for (int j = 0; j < 4; ++j) {
                    const int w = w0 + j;
                    if (w >= 0 && w < W_) v[j] = xr_[w];
                }
            }
        }
        *(f4*)&xs[c][hr][wq * 4] = v;
    }
    __syncthreads();

    if (tid >= 224) return;
    const int cq  = tid % 14;
    const int r   = (tid / 14) & 3;
    const int cg4 = tid / 56;

    // per-thread tap base: 4 cg4-lanes share each address (HW merges),
    // 4 r-rows per instruction coalesce into one 448B burst per k.
    const u16* wb = wgt + ((size_t)b * KG_ + (size_t)g * KK_) * HW_
                        + (r0 + r) * W_ + cq * 4;

    f4 acc[4] = {f4(0.f), f4(0.f), f4(0.f), f4(0.f)};
#pragma unroll
    for (int kh = 0; kh < Kk; ++kh) {
        float tf[7][4];
#pragma unroll
        for (int kw = 0; kw < 7; ++kw) {
            const u16x4 tv = *(const u16x4*)(wb + (size_t)(kh * 7 + kw) * HW_);
#pragma unroll
            for (int j = 0; j < 4; ++j) tf[kw][j] = bf2f(tv[j]);
        }
        const int hr = r + kh;
#pragma unroll
        for (int ci = 0; ci < 4; ++ci) {
            const float* xrow = &xs[cg4 * 4 + ci][hr][cq * 4];
            const f4 x0 = ld4(xrow), x1 = ld4(xrow + 4), x2 = ld4(xrow + 8);
            float xw[12];
#pragma unroll
            for (int j = 0; j < 4; ++j) { xw[j] = x0[j]; xw[4 + j] = x1[j]; xw[8 + j] = x2[j]; }
#pragma unroll
            for (int kw = 0; kw < 7; ++kw)
#pragma unroll
                for (int j = 0; j < 4; ++j)
                    acc[ci][j] = fmaf(tf[kw][j], xw[j + kw], acc[ci][j]);
        }
    }

#pragma unroll
    for (int ci = 0; ci < 4; ++ci)
        st4(out + (size_t)(b * C_ + g * GC_ + cg4 * 4 + ci) * HW_ + (r0 + r) * W_ + cq * 4,
            acc[ci]);
}

// ---------------------------------------------------------------------------
extern "C" void kernel_launch(void* const* d_in, const int* in_sizes, int n_in,
                              void* d_out, int out_size, void* d_ws, size_t ws_size,
                              hipStream_t stream) {
    const float* x  = (const float*)d_in[0];
    const float* w1 = (const float*)d_in[1];
    const float* b1 = (const float*)d_in[2];
    const float* w2 = (const float*)d_in[3];
    const float* b2 = (const float*)d_in[4];
    float* out = (float*)d_out;

    // ws: xt bf16 (6.42 MB) | t bf16 (1.6 MB) | wgt bf16 (19.7 MB)
    char* ws = (char*)d_ws;
    __bf16* xt  = (__bf16*)ws;
    __bf16* t   = (__bf16*)(ws + (size_t)NP_ * C_ * 2);
    __bf16* wgt = (__bf16*)(ws + (size_t)NP_ * C_ * 2 + (size_t)NP_ * RED_ * 2);

    xt_kernel  <<<dim3(NP_ / 64, C_ / 64), 256, 0, stream>>>(x, xt);
    gen1m2     <<<dim3(NP_ / 64),          256, 0, stream>>>(xt, w1, b1, t);
    gen2_mfma3 <<<dim3(NP_ / 256, 13),     256, 0, stream>>>(t, w2, b2, wgt);
    inv_kernel <<<dim3(14, G_, B_),        256, 0, stream>>>(x, (const u16*)wgt, out);
}

// Round 13
// 110.973 us; speedup vs baseline: 1.3844x; 1.0420x over previous
//
#include <hip/hip_runtime.h>

#define B_    4
#define C_    256
#define Kk    7
#define GC_   16
#define G_    16
#define RED_  64
#define H_    56
#define W_    56
#define HW_   3136
#define KK_   49
#define KG_   784
#define NP_   12544

typedef float  f4    __attribute__((ext_vector_type(4)));
typedef float  f32x4 __attribute__((ext_vector_type(4)));
typedef __bf16 bf16x8 __attribute__((ext_vector_type(8)));
typedef __bf16 bf16x4 __attribute__((ext_vector_type(4)));
typedef unsigned short u16;
typedef u16    u16x4 __attribute__((ext_vector_type(4)));
typedef u16    u16x8 __attribute__((ext_vector_type(8)));

__device__ __forceinline__ f4 ld4(const float* p) { return *(const f4*)p; }
__device__ __forceinline__ void st4(float* p, f4 v) { *(f4*)p = v; }
__device__ __forceinline__ float bf2f(u16 u) {
    return __uint_as_float(((unsigned)u) << 16);
}

// ---------------------------------------------------------------------------
// gen1f: fused x-transpose + gen1 MFMA.  t[P][64] bf16 = relu(w1 @ x + b1).
// Block = 64 px: stage x^T tile [64px][256c] bf16 in LDS (row 528B, 16B-
// aligned, <=2-way banks) + w1 in two 128-c halves. grid (196), block 256.
__global__ __launch_bounds__(256) void gen1f(const float* __restrict__ x,
                                             const float* __restrict__ w1,
                                             const float* __restrict__ b1,
                                             __bf16* __restrict__ t) {
    __shared__ __bf16 lt[64][264];         // 33792 B
    __shared__ __bf16 w1s[64][136];        // 17408 B  (total 51200 B)
    const int tid  = threadIdx.x;
    const int lane = tid & 63;
    const int wave = tid >> 6;
    const int row  = lane & 15;
    const int kg   = lane >> 4;
    const int P0   = blockIdx.x * 64;
    const int b    = P0 / HW_;             // 64 | 3136: block within one batch
    const int p0   = P0 - b * HW_;

    // stage x^T: 4 c-chunks x 4 sub-iters (xt_kernel pattern)
    const int pq  = tid & 15;
    const int crb = tid >> 4;
#pragma unroll
    for (int cc = 0; cc < 4; ++cc)
#pragma unroll
        for (int i = 0; i < 4; ++i) {
            const int c = cc * 64 + crb + i * 16;
            const f4 v = ld4(x + (size_t)(b * C_ + c) * HW_ + p0 + pq * 4);
#pragma unroll
            for (int j = 0; j < 4; ++j) lt[pq * 4 + j][c] = (__bf16)v[j];
        }
    // stage w1 half A (c 0..127): 2048 quads
#pragma unroll
    for (int i = 0; i < 8; ++i) {
        const int q  = tid + i * 256;
        const int r  = q >> 5;
        const int c0 = (q & 31) * 4;
        const f4 v = ld4(w1 + (size_t)r * C_ + c0);
        bf16x4 pk;
#pragma unroll
        for (int j = 0; j < 4; ++j) pk[j] = (__bf16)v[j];
        *(bf16x4*)&w1s[r][c0] = pk;
    }
    __syncthreads();

    f32x4 acc[4] = {f32x4(0.f), f32x4(0.f), f32x4(0.f), f32x4(0.f)};
#pragma unroll
    for (int ks = 0; ks < 4; ++ks) {
        const bf16x8 bv = *(const bf16x8*)&lt[wave * 16 + row][ks * 32 + kg * 8];
#pragma unroll
        for (int mt = 0; mt < 4; ++mt) {
            const bf16x8 af = *(const bf16x8*)&w1s[mt * 16 + row][ks * 32 + kg * 8];
            acc[mt] = __builtin_amdgcn_mfma_f32_16x16x32_bf16(af, bv, acc[mt], 0, 0, 0);
        }
    }
    __syncthreads();
    // stage w1 half B (c 128..255)
#pragma unroll
    for (int i = 0; i < 8; ++i) {
        const int q  = tid + i * 256;
        const int r  = q >> 5;
        const int c0 = (q & 31) * 4;
        const f4 v = ld4(w1 + (size_t)r * C_ + 128 + c0);
        bf16x4 pk;
#pragma unroll
        for (int j = 0; j < 4; ++j) pk[j] = (__bf16)v[j];
        *(bf16x4*)&w1s[r][c0] = pk;
    }
    __syncthreads();
#pragma unroll
    for (int ks = 4; ks < 8; ++ks) {
        const bf16x8 bv = *(const bf16x8*)&lt[wave * 16 + row][ks * 32 + kg * 8];
#pragma unroll
        for (int mt = 0; mt < 4; ++mt) {
            const bf16x8 af = *(const bf16x8*)&w1s[mt * 16 + row][(ks - 4) * 32 + kg * 8];
            acc[mt] = __builtin_amdgcn_mfma_f32_16x16x32_bf16(af, bv, acc[mt], 0, 0, 0);
        }
    }

#pragma unroll
    for (int mt = 0; mt < 4; ++mt) {
        const f4 bias = ld4(b1 + mt * 16 + kg * 4);
        bf16x4 pk;
#pragma unroll
        for (int j = 0; j < 4; ++j)
            pk[j] = (__bf16)fmaxf(acc[mt][j] + bias[j], 0.f);
        *(bf16x4*)(t + (size_t)(P0 + wave * 16 + row) * RED_ + mt * 16 + kg * 4) = pk;
    }
}

// ---------------------------------------------------------------------------
// gen2_mfma3: wgt = w2 @ t + b2, coalesced stores via per-wave LDS transpose.
// (r12, verified: per-WAVE batch index — 64 | 3136)
__global__ __launch_bounds__(256) void gen2_mfma3(const __bf16* __restrict__ t,
                                                  const float* __restrict__ w2,
                                                  const float* __restrict__ b2,
                                                  __bf16* __restrict__ wgt) {
    __shared__ __bf16 w2s[64][68];         // 8704 B
    __shared__ u16    sw[4][16][72];       // 9216 B
    const int tid  = threadIdx.x;
    const int lane = tid & 63;
    const int wave = tid >> 6;
    const int row  = lane & 15;
    const int kg   = lane >> 4;
    const int Pw   = blockIdx.x * 256 + wave * 64;   // wave's first global pixel
    const int b    = Pw / HW_;             // 64 | 3136: wave within one batch
    const int pw   = Pw - b * HW_;
    const int k0   = blockIdx.y * 64;
    const int nMt  = (blockIdx.y == 12) ? 1 : 4;     // 784 = 12*64 + 16

    bf16x8 bfrag[4][2];
#pragma unroll
    for (int cg = 0; cg < 4; ++cg)
#pragma unroll
        for (int ks = 0; ks < 2; ++ks)
            bfrag[cg][ks] = *(const bf16x8*)(t + (size_t)(Pw + cg * 16 + row) * RED_
                                               + ks * 32 + kg * 8);

#pragma unroll
    for (int i = 0; i < 4; ++i) {
        const int q  = tid + i * 256;
        const int r  = q >> 4;
        const int c0 = (q & 15) * 4;
        f4 v = {0.f, 0.f, 0.f, 0.f};
        if (k0 + r < KG_) v = ld4(w2 + (size_t)(k0 + r) * RED_ + c0);
        bf16x4 pk;
#pragma unroll
        for (int j = 0; j < 4; ++j) pk[j] = (__bf16)v[j];
        *(bf16x4*)&w2s[r][c0] = pk;
    }
    __syncthreads();

    for (int mt = 0; mt < nMt; ++mt) {
        const bf16x8 afr0 = *(const bf16x8*)&w2s[mt * 16 + row][kg * 8];
        const bf16x8 afr1 = *(const bf16x8*)&w2s[mt * 16 + row][32 + kg * 8];
        f32x4 acc[4] = {f32x4(0.f), f32x4(0.f), f32x4(0.f), f32x4(0.f)};
#pragma unroll
        for (int cg = 0; cg < 4; ++cg) {
            acc[cg] = __builtin_amdgcn_mfma_f32_16x16x32_bf16(afr0, bfrag[cg][0], acc[cg], 0, 0, 0);
            acc[cg] = __builtin_amdgcn_mfma_f32_16x16x32_bf16(afr1, bfrag[cg][1], acc[cg], 0, 0, 0);
        }
        const f4 bias = ld4(b2 + k0 + mt * 16 + kg * 4);
#pragma unroll
        for (int cg = 0; cg < 4; ++cg)
#pragma unroll
            for (int j = 0; j < 4; ++j) {
                const __bf16 v = (__bf16)(acc[cg][j] + bias[j]);
                sw[wave][kg * 4 + j][cg * 16 + row] = *(const u16*)&v;
            }
#pragma unroll
        for (int u = 0; u < 2; ++u) {
            const int r16 = (lane >> 3) + u * 8;
            const int ch  = lane & 7;
            const u16x8 v = *(const u16x8*)&sw[wave][r16][ch * 8];
            *(u16x8*)((u16*)wgt + ((size_t)b * KG_ + k0 + mt * 16 + r16) * HW_
                                + pw + ch * 8) = v;
        }
    }
}

// ---------------------------------------------------------------------------
// inv v4: channel-split. Block = (b, g, 4-row band, 8 of 16 channels).
// xs f32 [8][10][68] = 21.8KB -> 7 blocks/CU. Taps direct from global (L2).
// grid (14, 16, 8 = b*2 + chhalf), block 256.
#define BR_  4
#define XR_  10
#define XST_ 68
__global__ __launch_bounds__(256) void inv_kernel(const float* __restrict__ x,
                                                  const u16* __restrict__ wgt,
                                                  float* __restrict__ out) {
    __shared__ float xs[8][XR_][XST_];     // 21760 B
    const int tid = threadIdx.x;
    const int r0  = blockIdx.x * BR_;
    const int g   = blockIdx.y;
    const int z   = blockIdx.z;
    const int b   = z >> 1;
    const int ch0 = (z & 1) * 8;

    // stage xs: 8 ch x 10 rows x 16 col-quads = 1280 quads (f32, 16B ops)
    for (int idx = tid; idx < 8 * XR_ * 16; idx += 256) {
        const int c   = idx / (XR_ * 16);
        const int rem = idx - c * (XR_ * 16);
        const int hr  = rem >> 4;
        const int wq  = rem & 15;
        const int h   = r0 - 3 + hr;
        f4 v = {0.f, 0.f, 0.f, 0.f};
        if (h >= 0 && h < H_) {
            const float* xr_ = x + (size_t)(b * C_ + g * GC_ + ch0 + c) * HW_ + h * W_;
            const int w0 = wq * 4 - 3;
            if (wq >= 1 && wq <= 13) {
                v = ld4(xr_ + w0);
            } else {
#pragma unroll
                for (int j = 0; j < 4; ++j) {
                    const int w = w0 + j;
                    if (w >= 0 && w < W_) v[j] = xr_[w];
                }
            }
        }
        *(f4*)&xs[c][hr][wq * 4] = v;
    }
    __syncthreads();

    if (tid >= 224) return;
    const int cq = tid % 14;
    const int r  = (tid / 14) & 3;
    const int cg = tid / 56;               // 0..3, 2 channels each

    // tap base: 4 cg-lanes share each address (HW merges); 4 r-rows/instr
    // coalesce into one 448B burst per k.
    const u16* wb = wgt + ((size_t)b * KG_ + (size_t)g * KK_) * HW_
                        + (r0 + r) * W_ + cq * 4;

    f4 acc[2] = {f4(0.f), f4(0.f)};
#pragma unroll
    for (int kh = 0; kh < Kk; ++kh) {
        float tf[7][4];
#pragma unroll
        for (int kw = 0; kw < 7; ++kw) {
            const u16x4 tv = *(const u16x4*)(wb + (size_t)(kh * 7 + kw) * HW_);
#pragma unroll
            for (int j = 0; j < 4; ++j) tf[kw][j] = bf2f(tv[j]);
        }
        const int hr = r + kh;
#pragma unroll
        for (int ci = 0; ci < 2; ++ci) {
            const float* xrow = &xs[cg * 2 + ci][hr][cq * 4];
            const f4 x0 = ld4(xrow), x1 = ld4(xrow + 4), x2 = ld4(xrow + 8);
            float xw[12];
#pragma unroll
            for (int j = 0; j < 4; ++j) { xw[j] = x0[j]; xw[4 + j] = x1[j]; xw[8 + j] = x2[j]; }
#pragma unroll
            for (int kw = 0; kw < 7; ++kw)
#pragma unroll
                for (int j = 0; j < 4; ++j)
                    acc[ci][j] = fmaf(tf[kw][j], xw[j + kw], acc[ci][j]);
        }
    }

#pragma unroll
    for (int ci = 0; ci < 2; ++ci)
        st4(out + (size_t)(b * C_ + g * GC_ + ch0 + cg * 2 + ci) * HW_
                + (r0 + r) * W_ + cq * 4,
            acc[ci]);
}

// ---------------------------------------------------------------------------
extern "C" void kernel_launch(void* const* d_in, const int* in_sizes, int n_in,
                              void* d_out, int out_size, void* d_ws, size_t ws_size,
                              hipStream_t stream) {
    const float* x  = (const float*)d_in[0];
    const float* w1 = (const float*)d_in[1];
    const float* b1 = (const float*)d_in[2];
    const float* w2 = (const float*)d_in[3];
    const float* b2 = (const float*)d_in[4];
    float* out = (float*)d_out;

    // ws: t bf16 (1.6 MB) | wgt bf16 (19.7 MB)
    char* ws = (char*)d_ws;
    __bf16* t   = (__bf16*)ws;
    __bf16* wgt = (__bf16*)(ws + (size_t)NP_ * RED_ * 2);

    gen1f      <<<dim3(NP_ / 64),          256, 0, stream>>>(x, w1, b1, t);
    gen2_mfma3 <<<dim3(NP_ / 256, 13),     256, 0, stream>>>(t, w2, b2, wgt);
    inv_kernel <<<dim3(14, G_, 2 * B_),    256, 0, stream>>>(x, (const u16*)wgt, out);
}